// Round 8
// baseline (328.069 us; speedup 1.0000x reference)
//
#include <hip/hip_runtime.h>
#include <cstdint>

#define NB    32
#define NTOK  1024
#define D_    768
#define NHR   4096
#define HID   384
#define KSEL  154
#define MSEL  4928          // 32*154 = 77 * 64
#define MT_   77            // m-tiles of 64
#define FLAT  3072

typedef short  s16x8 __attribute__((ext_vector_type(8)));
typedef unsigned short u16x8 __attribute__((ext_vector_type(8)));
typedef unsigned short u16x4 __attribute__((ext_vector_type(4)));
typedef float  f32x4 __attribute__((ext_vector_type(4)));

__device__ inline unsigned short f2bf(float f) {
    uint32_t u = __builtin_bit_cast(uint32_t, f);
    u += 0x7FFFu + ((u >> 16) & 1u);          // RNE
    return (unsigned short)(u >> 16);
}
__device__ inline float bf2f(unsigned short h) {
    uint32_t u = ((uint32_t)h) << 16;
    return __builtin_bit_cast(float, u);
}
__device__ inline s16x8 cvt8(const float* __restrict__ p) {
    float4 v0 = *(const float4*)p, v1 = *(const float4*)(p + 4);
    s16x8 r;
    r[0]=(short)f2bf(v0.x); r[1]=(short)f2bf(v0.y); r[2]=(short)f2bf(v0.z); r[3]=(short)f2bf(v0.w);
    r[4]=(short)f2bf(v1.x); r[5]=(short)f2bf(v1.y); r[6]=(short)f2bf(v1.z); r[7]=(short)f2bf(v1.w);
    return r;
}

// ---- workspace layout (bytes) ----
#define OFF_SEL   0              // int[4928]
#define OFF_RMAP  32768          // int[32768]        131072
#define OFF_GPART 163840         // f32 [4928][12]    236544
#define OFF_FLAG  400384         // int [462]           1848
#define OFF_W1T   402432         // bf16 [384][3072]  2359296
#define OFF_W2T   2761728        // bf16 [768][384]    589824
#define OFF_WG1T  3351552        // bf16 [384][1536]  1179648
#define OFF_H     4531200        // bf16 [4928][384]  3784704
#define OFF_RL    8315904        // bf16 [4928][768]  7569408  (ends ~15.9 MB)
// ---- d_out scratch: Aloc bf16[4928][3072] at 0 (30.3 MB); P0/P1 f32[4928][384]
//      partials after it — all consumed before finalize writes d_out.
#define DOUT_P0   32505856
#define DOUT_P1   (DOUT_P0 + MSEL * HID * 4)

// ---------------- prep: topk (blocks 0-31) + weight cvt (blocks 32+) + zero flags ----------------
__global__ __launch_bounds__(1024) void prep_kernel(
    const float* __restrict__ scores, int* __restrict__ sel, int* __restrict__ rmap,
    const float* __restrict__ W1, const float* __restrict__ W2, const float* __restrict__ Wg1,
    unsigned short* __restrict__ W1t, unsigned short* __restrict__ W2t,
    unsigned short* __restrict__ Wg1t, int* __restrict__ flags)
{
    __shared__ float s[NTOK];
    __shared__ int cnt;
    __shared__ unsigned short T[4][64][66];
    const int bid = blockIdx.x;
    if (bid < NB) {
        const int b = bid;
        const int t = threadIdx.x;
        if (b == 0 && t < MT_ * 6) flags[t] = 0;   // zero split-K flags every call
        s[t] = scores[b * NTOK + t];
        if (t == 0) cnt = 0;
        __syncthreads();
        float v = s[t];
        int rank = 0;
        for (int j = 0; j < NTOK; ++j) {
            float vj = s[j];
            rank += (vj > v) || (vj == v && j < t);
        }
        int rm = -1;
        if (rank < KSEL) {
            int pos = atomicAdd(&cnt, 1);
            rm = b * KSEL + pos;
            sel[rm] = t;
        }
        rmap[b * NTOK + t] = rm;
    } else {
        const int g = threadIdx.x >> 8;
        const int tid = threadIdx.x & 255;
        const int tile = (bid - NB) * 4 + g;     // 0..503
        const float* src; unsigned short* dst; int K, N, kt, nt;
        if (tile < 288)      { src = W1;  dst = W1t;  K = FLAT; N = HID; nt = tile % 6;  kt = tile / 6;  }
        else if (tile < 360) { int l = tile - 288; src = W2;  dst = W2t;  K = HID;  N = D_;  nt = l % 12; kt = l / 12; }
        else                 { int l = tile - 360; src = Wg1; dst = Wg1t; K = 1536; N = HID; nt = l % 6;  kt = l / 6;  }
        const int k0 = kt * 64, n0 = nt * 64;
        {
            const int ln = tid & 63, kc = tid >> 6;
            #pragma unroll
            for (int j = 0; j < 16; ++j)
                T[g][ln][kc * 16 + j] = f2bf(src[(uint64_t)(k0 + kc * 16 + j) * N + n0 + ln]);
        }
        __syncthreads();
        {
            const int row = tid >> 2, c0 = (tid & 3) * 16;
            u16x8 v0, v1;
            #pragma unroll
            for (int p = 0; p < 8; ++p) { v0[p] = T[g][row][c0 + p]; v1[p] = T[g][row][c0 + 8 + p]; }
            *(u16x8*)(dst + (uint64_t)(n0 + row) * K + k0 + c0) = v0;
            *(u16x8*)(dst + (uint64_t)(n0 + row) * K + k0 + c0 + 8) = v1;
        }
    }
}

// ---------------- gather selected patch rows -> bf16 Aloc ----------------
__global__ __launch_bounds__(256) void gather_kernel(
    const int* __restrict__ sel, const float* __restrict__ highres,
    unsigned short* __restrict__ Aloc) {
    const int r = blockIdx.x;
    const int b = r / KSEL;
    const int t = sel[r];
    const int gy = t >> 5, gx = t & 31;
    for (int ch = threadIdx.x; ch < 384; ch += 256) {
        int k8 = ch * 8;
        int p = k8 / D_;
        int col = k8 - p * D_;
        int hr = (gy * 2 + (p >> 1)) * 64 + gx * 2 + (p & 1);
        s16x8 v = cvt8(highres + ((uint64_t)b * NHR + hr) * D_ + col);
        *(s16x8*)(Aloc + (uint64_t)r * FLAT + k8) = v;
    }
}

// ---------------- MFMA GEMM: 64x64x64 tiles, 4 waves (2x2), XCD-grouped ----------------
// MODE 0: split-K=2 partials of Aloc@W1t; last-finisher writes h=bf16(GELU(P0+P1+b1))
// MODE 1: rl = h[4928x384] @ W2t + b2   bf16 out
// MODE 2: SiLU([base_f32|rl] @ Wg1t + score*Wg1[1536] + bg1) -> gate partials
template <int MODE>
__global__ __launch_bounds__(256) void gemm_mfma(
    const float* __restrict__ Araw,          // mode2: base
    const unsigned short* __restrict__ Abf,  // mode0: Aloc; mode1: h; mode2: rl
    const unsigned short* __restrict__ Bt,
    const float* __restrict__ bias,
    const int* __restrict__ sel,
    const float* __restrict__ scores,
    const float* __restrict__ WgLast,
    const float* __restrict__ Wg2,
    void* __restrict__ Cout,
    float* __restrict__ Pout,
    float* __restrict__ gpart,
    int* __restrict__ flags)
{
    constexpr int K = MODE == 0 ? FLAT : (MODE == 1 ? HID : 2 * D_);   // logical K / B stride
    constexpr int N = MODE == 1 ? D_ : HID;
    constexpr int NT = N / 64;
    constexpr int KLEN = (MODE == 0) ? 1536 : K;
    constexpr int NSTEP = KLEN / 64;

    // XCD-grouping: same m-tile -> same XCD (lin%8)
    const int lin = blockIdx.x;
    const int xcd = lin & 7;
    int j = lin >> 3;
    const int ntile = j % NT; j /= NT;
    const int mhi = j % 10;
    const int split = j / 10;                 // 0 unless MODE 0
    const int mt = mhi * 8 + xcd;
    if (mt >= MT_) return;
    const int m0 = mt * 64;
    const int n0 = ntile * 64;
    const int kb = (MODE == 0) ? split * 1536 : 0;

    __shared__ unsigned short As[2][64 * 64];
    __shared__ unsigned short Bs[2][64 * 64];
    __shared__ uint32_t offT[64];
    __shared__ float scv[64];
    __shared__ int who;

    const int tid = threadIdx.x;
    const int lane = tid & 63;
    const int wid = tid >> 6;
    const int wm = wid >> 1;
    const int wn = wid & 1;

    if (MODE == 2) {
        if (tid < 64) {
            int r = m0 + tid, b = r / KSEL, t = sel[r];
            offT[tid] = (uint32_t)(b * NTOK + t) * D_;
            scv[tid] = scores[b * NTOK + t];
        }
        __syncthreads();
    }

    const int sr0 = tid >> 3;   // row 0..31 (+32 for second half)
    const int sc0 = tid & 7;    // 16B chunk 0..7

    auto loadA = [&](int k0, int half, s16x8& dst) {
        int r = sr0 + half * 32;
        int k = k0 + sc0 * 8;
        if (MODE == 0) {
            dst = *(const s16x8*)(Abf + (uint64_t)(m0 + r) * FLAT + k);
        } else if (MODE == 1) {
            dst = *(const s16x8*)(Abf + (uint64_t)(m0 + r) * HID + k);
        } else {
            if (k < D_) dst = cvt8(Araw + offT[r] + k);
            else        dst = *(const s16x8*)(Abf + (uint64_t)(m0 + r) * D_ + (k - D_));
        }
    };
    auto loadB = [&](int k0, int half, s16x8& dst) {
        int r = sr0 + half * 32;
        dst = *(const s16x8*)(Bt + (uint64_t)(n0 + r) * K + k0 + sc0 * 8);
    };
    auto writeTile = [&](int buf, s16x8* a, s16x8* b) {
        #pragma unroll
        for (int half = 0; half < 2; ++half) {
            int r = sr0 + half * 32;
            int c = sc0 ^ (r & 7);                 // XOR swizzle (write side)
            *(s16x8*)&As[buf][r * 64 + c * 8] = a[half];
            *(s16x8*)&Bs[buf][r * 64 + c * 8] = b[half];
        }
    };

    f32x4 acc[2][2];
    #pragma unroll
    for (int i = 0; i < 2; ++i)
        #pragma unroll
        for (int jj = 0; jj < 2; ++jj) acc[i][jj] = (f32x4){0.f, 0.f, 0.f, 0.f};

    s16x8 aR[2], bR[2];
    loadA(kb, 0, aR[0]); loadA(kb, 1, aR[1]);
    loadB(kb, 0, bR[0]); loadB(kb, 1, bR[1]);
    writeTile(0, aR, bR);
    __syncthreads();
    if (NSTEP > 1) {
        loadA(kb + 64, 0, aR[0]); loadA(kb + 64, 1, aR[1]);
        loadB(kb + 64, 0, bR[0]); loadB(kb + 64, 1, bR[1]);
    }

    int cur = 0;
    for (int t = 0; t < NSTEP; ++t) {
        #pragma unroll
        for (int kk = 0; kk < 2; ++kk) {
            s16x8 af[2], bfr[2];
            #pragma unroll
            for (int i = 0; i < 2; ++i) {
                int row  = wm * 32 + i * 16 + (lane & 15);
                int cch  = (kk * 4 + (lane >> 4)) ^ (row & 7);   // XOR swizzle (read side)
                af[i] = *(const s16x8*)&As[cur][row * 64 + cch * 8];
                int nrow = wn * 32 + i * 16 + (lane & 15);
                int cchb = (kk * 4 + (lane >> 4)) ^ (nrow & 7);
                bfr[i] = *(const s16x8*)&Bs[cur][nrow * 64 + cchb * 8];
            }
            #pragma unroll
            for (int i = 0; i < 2; ++i)
                #pragma unroll
                for (int jj = 0; jj < 2; ++jj)
                    acc[i][jj] = __builtin_amdgcn_mfma_f32_16x16x32_bf16(af[i], bfr[jj], acc[i][jj], 0, 0, 0);
        }
        if (t + 1 < NSTEP) {
            writeTile(cur ^ 1, aR, bR);
            __syncthreads();
            if (t + 2 < NSTEP) {
                int k0 = kb + (t + 2) * 64;
                loadA(k0, 0, aR[0]); loadA(k0, 1, aR[1]);
                loadB(k0, 0, bR[0]); loadB(k0, 1, bR[1]);
            }
            cur ^= 1;
        }
    }

    // epilogue: C row = (lane>>4)*4+reg, col = lane&15
    if (MODE == 0) {
        float* P = Pout + (uint64_t)split * (MSEL * HID);
        #pragma unroll
        for (int i = 0; i < 2; ++i)
            #pragma unroll
            for (int jj = 0; jj < 2; ++jj)
                #pragma unroll
                for (int reg = 0; reg < 4; ++reg) {
                    int m = m0 + wm * 32 + i * 16 + (lane >> 4) * 4 + reg;
                    int n = n0 + wn * 32 + jj * 16 + (lane & 15);
                    P[(uint64_t)m * HID + n] = acc[i][jj][reg];
                }
        __threadfence();
        __syncthreads();
        if (tid == 0) who = atomicAdd(&flags[mt * 6 + ntile], 1);
        __syncthreads();
        if (who == 1) {                       // second arriver: both partials visible
            __threadfence();
            const float* Pa = Pout;
            const float* Pb = Pout + MSEL * HID;
            const int r = tid >> 2;
            const int c0 = (tid & 3) * 16;
            const uint64_t o = (uint64_t)(m0 + r) * HID + (n0 + c0);
            unsigned short* H = (unsigned short*)Cout;
            #pragma unroll
            for (int hseg = 0; hseg < 2; ++hseg) {
                u16x8 v;
                #pragma unroll
                for (int p = 0; p < 8; ++p) {
                    float x = Pa[o + hseg * 8 + p] + Pb[o + hseg * 8 + p]
                            + bias[n0 + c0 + hseg * 8 + p];
                    x = 0.5f * x * (1.0f + erff(x * 0.70710678118654752f));
                    v[p] = f2bf(x);
                }
                *(u16x8*)(H + o + hseg * 8) = v;
            }
        }
        return;
    }
    if (MODE == 2) {
        float wg2v[2] = { Wg2[n0 + wn * 32 + (lane & 15)],
                          Wg2[n0 + wn * 32 + 16 + (lane & 15)] };
        float psum[2][4];
        #pragma unroll
        for (int i = 0; i < 2; ++i)
            #pragma unroll
            for (int reg = 0; reg < 4; ++reg) psum[i][reg] = 0.f;
        #pragma unroll
        for (int i = 0; i < 2; ++i) {
            #pragma unroll
            for (int jj = 0; jj < 2; ++jj) {
                #pragma unroll
                for (int reg = 0; reg < 4; ++reg) {
                    int m = m0 + wm * 32 + i * 16 + (lane >> 4) * 4 + reg;
                    int n = n0 + wn * 32 + jj * 16 + (lane & 15);
                    float x = acc[i][jj][reg] + bias[n] + scv[m - m0] * WgLast[n];
                    x = x / (1.0f + __expf(-x));          // SiLU -> hg value
                    psum[i][reg] += x * wg2v[jj];
                }
            }
        }
        #pragma unroll
        for (int mask = 1; mask < 16; mask <<= 1)
            #pragma unroll
            for (int i = 0; i < 2; ++i)
                #pragma unroll
                for (int reg = 0; reg < 4; ++reg)
                    psum[i][reg] += __shfl_xor(psum[i][reg], mask);
        if ((lane & 15) == 0) {
            #pragma unroll
            for (int i = 0; i < 2; ++i)
                #pragma unroll
                for (int reg = 0; reg < 4; ++reg) {
                    int m = m0 + wm * 32 + i * 16 + (lane >> 4) * 4 + reg;
                    gpart[m * 12 + ntile * 2 + wn] = psum[i][reg];
                }
        }
        return;
    }
    #pragma unroll
    for (int i = 0; i < 2; ++i)
        #pragma unroll
        for (int jj = 0; jj < 2; ++jj)
            #pragma unroll
            for (int reg = 0; reg < 4; ++reg) {
                int m = m0 + wm * 32 + i * 16 + (lane >> 4) * 4 + reg;
                int n = n0 + wn * 32 + jj * 16 + (lane & 15);
                float x = acc[i][jj][reg] + bias[n];
                ((unsigned short*)Cout)[(uint64_t)m * D_ + n] = f2bf(x);
            }
}

// ---------------- finalize: out = base, blended on selected rows ----------------
__global__ __launch_bounds__(256) void finalize_kernel(
    const int* __restrict__ rmap,
    const float* __restrict__ gpart, const float* __restrict__ bg2,
    const float* __restrict__ base, const unsigned short* __restrict__ rl,
    float* __restrict__ out)
{
    const int lane = threadIdx.x & 63;
    const int row = blockIdx.x * 4 + (threadIdx.x >> 6);
    const int rm = rmap[row];

    const uint64_t bo = (uint64_t)row * D_;
    const float4* b4 = (const float4*)(base + bo);
    float4* o4 = (float4*)(out + bo);

    if (rm < 0) {
        #pragma unroll
        for (int i = 0; i < 3; ++i) o4[lane + 64 * i] = b4[lane + 64 * i];
        return;
    }
    const float4* gp = (const float4*)(gpart + (uint64_t)rm * 12);
    float4 g0 = gp[0], g1 = gp[1], g2 = gp[2];
    float sum = g0.x + g0.y + g0.z + g0.w + g1.x + g1.y + g1.z + g1.w
              + g2.x + g2.y + g2.z + g2.w + bg2[0];
    float gate = 1.0f / (1.0f + __expf(-sum));

    const u16x4* r4 = (const u16x4*)(rl + (uint64_t)rm * D_);
    #pragma unroll
    for (int i = 0; i < 3; ++i) {
        int idx = lane + 64 * i;
        float4 bb = b4[idx];
        u16x4 rr = r4[idx];
        float4 oo;
        oo.x = bb.x + gate * (bf2f(rr[0]) - bb.x);
        oo.y = bb.y + gate * (bf2f(rr[1]) - bb.y);
        oo.z = bb.z + gate * (bf2f(rr[2]) - bb.z);
        oo.w = bb.w + gate * (bf2f(rr[3]) - bb.w);
        o4[idx] = oo;
    }
}

extern "C" void kernel_launch(void* const* d_in, const int* in_sizes, int n_in,
                              void* d_out, int out_size, void* d_ws, size_t ws_size,
                              hipStream_t stream) {
    const float* base   = (const float*)d_in[0];
    const float* hires  = (const float*)d_in[1];
    const float* scores = (const float*)d_in[2];
    const float* W1  = (const float*)d_in[3];
    const float* b1  = (const float*)d_in[4];
    const float* W2  = (const float*)d_in[5];
    const float* b2  = (const float*)d_in[6];
    const float* Wg1 = (const float*)d_in[7];
    const float* bg1 = (const float*)d_in[8];
    const float* Wg2 = (const float*)d_in[9];
    const float* bg2 = (const float*)d_in[10];
    float* out = (float*)d_out;

    char* ws = (char*)d_ws;
    int*            sel   = (int*)(ws + OFF_SEL);
    int*            rmap  = (int*)(ws + OFF_RMAP);
    float*          gpart = (float*)(ws + OFF_GPART);
    int*            flags = (int*)(ws + OFF_FLAG);
    unsigned short* W1t   = (unsigned short*)(ws + OFF_W1T);
    unsigned short* W2t   = (unsigned short*)(ws + OFF_W2T);
    unsigned short* Wg1t  = (unsigned short*)(ws + OFF_WG1T);
    unsigned short* h     = (unsigned short*)(ws + OFF_H);
    unsigned short* rl    = (unsigned short*)(ws + OFF_RL);
    unsigned short* Aloc  = (unsigned short*)d_out;             // scratch until finalize
    float*          P0    = (float*)((char*)d_out + DOUT_P0);

    prep_kernel<<<dim3(NB + 126), dim3(1024), 0, stream>>>(scores, sel, rmap,
                                                           W1, W2, Wg1, W1t, W2t, Wg1t, flags);
    gather_kernel<<<dim3(MSEL), dim3(256), 0, stream>>>(sel, hires, Aloc);
    gemm_mfma<0><<<dim3(8 * 10 * 6 * 2), dim3(256), 0, stream>>>(
        nullptr, Aloc, W1t, b1, nullptr, nullptr, nullptr, nullptr, h, P0, nullptr, flags);
    gemm_mfma<1><<<dim3(8 * 10 * 12), dim3(256), 0, stream>>>(
        nullptr, h, W2t, b2, nullptr, nullptr, nullptr, nullptr, rl, nullptr, nullptr, nullptr);
    gemm_mfma<2><<<dim3(8 * 10 * 6), dim3(256), 0, stream>>>(
        base, rl, Wg1t, bg1, sel, scores, Wg1 + (uint64_t)1536 * HID, Wg2,
        nullptr, nullptr, gpart, nullptr);
    finalize_kernel<<<dim3(NB * NTOK / 4), dim3(256), 0, stream>>>(rmap, gpart, bg2, base, rl, out);
}

// Round 9
// 148.388 us; speedup vs baseline: 2.2109x; 2.2109x over previous
//
#include <hip/hip_runtime.h>
#include <cstdint>

#define NB    32
#define NTOK  1024
#define D_    768
#define NHR   4096
#define HID   384
#define KSEL  154
#define MSEL  4928          // 32*154 = 77 * 64
#define MT_   77            // m-tiles of 64
#define FLAT  3072

typedef short  s16x8 __attribute__((ext_vector_type(8)));
typedef unsigned short u16x8 __attribute__((ext_vector_type(8)));
typedef unsigned short u16x4 __attribute__((ext_vector_type(4)));
typedef float  f32x4 __attribute__((ext_vector_type(4)));

__device__ inline unsigned short f2bf(float f) {
    uint32_t u = __builtin_bit_cast(uint32_t, f);
    u += 0x7FFFu + ((u >> 16) & 1u);          // RNE
    return (unsigned short)(u >> 16);
}
__device__ inline float bf2f(unsigned short h) {
    uint32_t u = ((uint32_t)h) << 16;
    return __builtin_bit_cast(float, u);
}
__device__ inline s16x8 cvt8(const float* __restrict__ p) {
    float4 v0 = *(const float4*)p, v1 = *(const float4*)(p + 4);
    s16x8 r;
    r[0]=(short)f2bf(v0.x); r[1]=(short)f2bf(v0.y); r[2]=(short)f2bf(v0.z); r[3]=(short)f2bf(v0.w);
    r[4]=(short)f2bf(v1.x); r[5]=(short)f2bf(v1.y); r[6]=(short)f2bf(v1.z); r[7]=(short)f2bf(v1.w);
    return r;
}

// ---- workspace layout (bytes) ----
#define OFF_SEL   0              // int[4928]
#define OFF_RMAP  32768          // int[32768]        131072
#define OFF_GPART 163840         // f32 [4928][12]    236544
#define OFF_W1T   401408         // bf16 [384][3072]  2359296
#define OFF_W2T   2760704        // bf16 [768][384]    589824
#define OFF_WG1T  3350528        // bf16 [384][1536]  1179648
#define OFF_ABASE 4530176        // bf16 [4928][768]  7569408
#define OFF_H     12099584       // bf16 [4928][384]  3784704
#define OFF_RL    15884288       // bf16 [4928][768]  7569408  (ends ~23.5 MB)
// ---- d_out scratch: Aloc bf16[4928][3072] at 0 (30.3 MB); P0/P1/P2 f32[4928][384]
//      partials after it — all consumed before finalize writes d_out.
#define DOUT_P0   32505856
#define PSTRIDE   (MSEL * HID)   // floats per split partial

// ---------------- prep: blocks 0-31 topk, blocks 32+ weight transpose+cvt ----------------
__global__ __launch_bounds__(1024) void prep_kernel(
    const float* __restrict__ scores, int* __restrict__ sel, int* __restrict__ rmap,
    const float* __restrict__ W1, const float* __restrict__ W2, const float* __restrict__ Wg1,
    unsigned short* __restrict__ W1t, unsigned short* __restrict__ W2t,
    unsigned short* __restrict__ Wg1t)
{
    __shared__ float s[NTOK];
    __shared__ int cnt;
    __shared__ unsigned short T[4][64][66];
    const int bid = blockIdx.x;
    if (bid < NB) {
        const int b = bid;
        const int t = threadIdx.x;
        s[t] = scores[b * NTOK + t];
        if (t == 0) cnt = 0;
        __syncthreads();
        float v = s[t];
        int rank = 0;
        for (int j = 0; j < NTOK; ++j) {
            float vj = s[j];
            rank += (vj > v) || (vj == v && j < t);
        }
        int rm = -1;
        if (rank < KSEL) {
            int pos = atomicAdd(&cnt, 1);
            rm = b * KSEL + pos;
            sel[rm] = t;
        }
        rmap[b * NTOK + t] = rm;
    } else {
        const int g = threadIdx.x >> 8;
        const int tid = threadIdx.x & 255;
        const int tile = (bid - NB) * 4 + g;     // 0..503
        const float* src; unsigned short* dst; int K, N, kt, nt;
        if (tile < 288)      { src = W1;  dst = W1t;  K = FLAT; N = HID; nt = tile % 6;  kt = tile / 6;  }
        else if (tile < 360) { int l = tile - 288; src = W2;  dst = W2t;  K = HID;  N = D_;  nt = l % 12; kt = l / 12; }
        else                 { int l = tile - 360; src = Wg1; dst = Wg1t; K = 1536; N = HID; nt = l % 6;  kt = l / 6;  }
        const int k0 = kt * 64, n0 = nt * 64;
        {
            const int ln = tid & 63, kc = tid >> 6;
            #pragma unroll
            for (int j = 0; j < 16; ++j)
                T[g][ln][kc * 16 + j] = f2bf(src[(uint64_t)(k0 + kc * 16 + j) * N + n0 + ln]);
        }
        __syncthreads();
        {
            const int row = tid >> 2, c0 = (tid & 3) * 16;
            u16x8 v0, v1;
            #pragma unroll
            for (int p = 0; p < 8; ++p) { v0[p] = T[g][row][c0 + p]; v1[p] = T[g][row][c0 + 8 + p]; }
            *(u16x8*)(dst + (uint64_t)(n0 + row) * K + k0 + c0) = v0;
            *(u16x8*)(dst + (uint64_t)(n0 + row) * K + k0 + c0 + 8) = v1;
        }
    }
}

// ---------------- gather selected rows -> bf16 Aloc (patches) + Abase ----------------
__global__ __launch_bounds__(256) void gather_kernel(
    const int* __restrict__ sel, const float* __restrict__ highres,
    const float* __restrict__ base,
    unsigned short* __restrict__ Aloc, unsigned short* __restrict__ Abase) {
    const int r = blockIdx.x;
    const int b = r / KSEL;
    const int t = sel[r];
    const int gy = t >> 5, gx = t & 31;
    for (int ch = threadIdx.x; ch < 480; ch += 256) {
        if (ch < 384) {
            int k8 = ch * 8;
            int p = k8 / D_;
            int col = k8 - p * D_;
            int hr = (gy * 2 + (p >> 1)) * 64 + gx * 2 + (p & 1);
            s16x8 v = cvt8(highres + ((uint64_t)b * NHR + hr) * D_ + col);
            *(s16x8*)(Aloc + (uint64_t)r * FLAT + k8) = v;
        } else {
            int col = (ch - 384) * 8;
            s16x8 v = cvt8(base + ((uint64_t)b * NTOK + t) * D_ + col);
            *(s16x8*)(Abase + (uint64_t)r * D_ + col) = v;
        }
    }
}

// ---------------- MFMA GEMM, XCD-grouped ----------------
// MODE 0: BM=64,BN=128, split-K=3: P[split] = Aloc @ W1t (f32 partials)
// MODE 1: BM=64,BN=128: rl = h @ W2t + b2 (bf16)
// MODE 2: BM=64,BN=64:  SiLU([Abase|rl] @ Wg1t + score*Wg1[1536] + bg1) -> gate partials
template <int MODE>
__global__ __launch_bounds__(256) void gemm_mfma(
    const unsigned short* __restrict__ A0,   // mode0: Aloc; mode1: h; mode2: Abase
    const unsigned short* __restrict__ A1,   // mode2: rl
    const unsigned short* __restrict__ Bt,
    const float* __restrict__ bias,
    const int* __restrict__ sel,
    const float* __restrict__ scores,
    const float* __restrict__ WgLast,
    const float* __restrict__ Wg2,
    void* __restrict__ Cout,
    float* __restrict__ Pout,
    float* __restrict__ gpart)
{
    constexpr int K = MODE == 0 ? FLAT : (MODE == 1 ? HID : 2 * D_);   // row stride / logical K
    constexpr int N = MODE == 1 ? D_ : HID;
    constexpr int BN = (MODE == 2) ? 64 : 128;
    constexpr int NFRAG = BN / 32;            // frags per wave in n (2 or 4)
    constexpr int NT = N / BN;
    constexpr int KLEN = (MODE == 0) ? 1024 : K;
    constexpr int NSTEP = KLEN / 64;
    constexpr int NSPLIT = (MODE == 0) ? 3 : 1;

    // XCD-grouping: same m-tile -> same XCD (lin%8)
    const int lin = blockIdx.x;
    const int xcd = lin & 7;
    int j = lin >> 3;
    const int ntile = j % NT; j /= NT;
    const int mhi = j % 10;
    const int split = j / 10;                 // < NSPLIT
    const int mt = mhi * 8 + xcd;
    if (mt >= MT_) return;
    const int m0 = mt * 64;
    const int n0 = ntile * BN;
    const int kb = split * KLEN;

    __shared__ unsigned short As[2][64 * 64];
    __shared__ unsigned short Bs[2][BN * 64];
    __shared__ float scv[64];

    const int tid = threadIdx.x;
    const int lane = tid & 63;
    const int wid = tid >> 6;
    const int wm = wid >> 1;                  // 0..1: rows wm*32
    const int wn = wid & 1;                   // 0..1: cols wn*(BN/2)

    if (MODE == 2 && tid < 64) {
        int r = m0 + tid, b = r / KSEL, t = sel[r];
        scv[tid] = scores[b * NTOK + t];
    }

    const int sr0 = tid >> 3;   // 0..31
    const int sc0 = tid & 7;    // 16B chunk

    s16x8 aR[2], bR[NFRAG];
    auto loadTile = [&](int k0) {
        #pragma unroll
        for (int half = 0; half < 2; ++half) {
            int r = sr0 + half * 32;
            int k = k0 + sc0 * 8;
            const unsigned short* p;
            if (MODE == 0)      p = A0 + (uint64_t)(m0 + r) * FLAT + k;
            else if (MODE == 1) p = A0 + (uint64_t)(m0 + r) * HID + k;
            else {
                p = (k < D_) ? (A0 + (uint64_t)(m0 + r) * D_ + k)
                             : (A1 + (uint64_t)(m0 + r) * D_ + (k - D_));
            }
            aR[half] = *(const s16x8*)p;
        }
        #pragma unroll
        for (int it = 0; it < NFRAG; ++it) {
            int r = it * 32 + sr0;
            bR[it] = *(const s16x8*)(Bt + (uint64_t)(n0 + r) * K + k0 + sc0 * 8);
        }
    };
    auto writeTile = [&](int buf) {
        #pragma unroll
        for (int half = 0; half < 2; ++half) {
            int r = sr0 + half * 32;
            int c = sc0 ^ (r & 7);                 // XOR swizzle (write side)
            *(s16x8*)&As[buf][r * 64 + c * 8] = aR[half];
        }
        #pragma unroll
        for (int it = 0; it < NFRAG; ++it) {
            int r = it * 32 + sr0;
            int c = sc0 ^ (r & 7);
            *(s16x8*)&Bs[buf][r * 64 + c * 8] = bR[it];
        }
    };

    f32x4 acc[2][NFRAG];
    #pragma unroll
    for (int i = 0; i < 2; ++i)
        #pragma unroll
        for (int jj = 0; jj < NFRAG; ++jj) acc[i][jj] = (f32x4){0.f, 0.f, 0.f, 0.f};

    loadTile(kb);
    writeTile(0);
    __syncthreads();
    if (NSTEP > 1) loadTile(kb + 64);

    int cur = 0;
    for (int t = 0; t < NSTEP; ++t) {
        #pragma unroll
        for (int kk = 0; kk < 2; ++kk) {
            s16x8 af[2], bfr[NFRAG];
            #pragma unroll
            for (int i = 0; i < 2; ++i) {
                int row = wm * 32 + i * 16 + (lane & 15);
                int cch = (kk * 4 + (lane >> 4)) ^ (row & 7);   // XOR swizzle (read side)
                af[i] = *(const s16x8*)&As[cur][row * 64 + cch * 8];
            }
            #pragma unroll
            for (int jj = 0; jj < NFRAG; ++jj) {
                int nrow = wn * (BN / 2) + jj * 16 + (lane & 15);
                int cch = (kk * 4 + (lane >> 4)) ^ (nrow & 7);
                bfr[jj] = *(const s16x8*)&Bs[cur][nrow * 64 + cch * 8];
            }
            #pragma unroll
            for (int i = 0; i < 2; ++i)
                #pragma unroll
                for (int jj = 0; jj < NFRAG; ++jj)
                    acc[i][jj] = __builtin_amdgcn_mfma_f32_16x16x32_bf16(af[i], bfr[jj], acc[i][jj], 0, 0, 0);
        }
        if (t + 1 < NSTEP) {
            writeTile(cur ^ 1);
            __syncthreads();
            if (t + 2 < NSTEP) loadTile(kb + (t + 2) * 64);
            cur ^= 1;
        }
    }

    // epilogue: C row = (lane>>4)*4+reg, col = lane&15
    if (MODE == 2) {
        float wg2v[2] = { Wg2[n0 + wn * 32 + (lane & 15)],
                          Wg2[n0 + wn * 32 + 16 + (lane & 15)] };
        float psum[2][4];
        #pragma unroll
        for (int i = 0; i < 2; ++i)
            #pragma unroll
            for (int reg = 0; reg < 4; ++reg) psum[i][reg] = 0.f;
        #pragma unroll
        for (int i = 0; i < 2; ++i) {
            #pragma unroll
            for (int jj = 0; jj < 2; ++jj) {
                #pragma unroll
                for (int reg = 0; reg < 4; ++reg) {
                    int m = m0 + wm * 32 + i * 16 + (lane >> 4) * 4 + reg;
                    int n = n0 + wn * 32 + jj * 16 + (lane & 15);
                    float x = acc[i][jj][reg] + bias[n] + scv[m - m0] * WgLast[n];
                    x = x / (1.0f + __expf(-x));          // SiLU -> hg value
                    psum[i][reg] += x * wg2v[jj];
                }
            }
        }
        #pragma unroll
        for (int mask = 1; mask < 16; mask <<= 1)
            #pragma unroll
            for (int i = 0; i < 2; ++i)
                #pragma unroll
                for (int reg = 0; reg < 4; ++reg)
                    psum[i][reg] += __shfl_xor(psum[i][reg], mask);
        if ((lane & 15) == 0) {
            #pragma unroll
            for (int i = 0; i < 2; ++i)
                #pragma unroll
                for (int reg = 0; reg < 4; ++reg) {
                    int m = m0 + wm * 32 + i * 16 + (lane >> 4) * 4 + reg;
                    gpart[m * 12 + ntile * 2 + wn] = psum[i][reg];
                }
        }
        return;
    }
    float* P = (MODE == 0) ? (Pout + (uint64_t)split * PSTRIDE) : nullptr;
    #pragma unroll
    for (int i = 0; i < 2; ++i)
        #pragma unroll
        for (int jj = 0; jj < NFRAG; ++jj)
            #pragma unroll
            for (int reg = 0; reg < 4; ++reg) {
                int m = m0 + wm * 32 + i * 16 + (lane >> 4) * 4 + reg;
                int n = n0 + wn * (BN / 2) + jj * 16 + (lane & 15);
                if (MODE == 0) {
                    P[(uint64_t)m * HID + n] = acc[i][jj][reg];   // raw partial
                } else {
                    float x = acc[i][jj][reg] + bias[n];
                    ((unsigned short*)Cout)[(uint64_t)m * D_ + n] = f2bf(x);
                }
            }
}

// ---------------- combine: h = bf16(GELU(P0 + P1 + P2 + b1)) ----------------
__global__ __launch_bounds__(256) void combine_kernel(
    const float* __restrict__ P, const float* __restrict__ b1,
    unsigned short* __restrict__ h)
{
    const int idx = (blockIdx.x * 256 + threadIdx.x) * 8;   // < 4928*384, exact
    const int col = idx % HID;
    float4 a0 = *(const float4*)(P + idx),               a1 = *(const float4*)(P + idx + 4);
    float4 c0 = *(const float4*)(P + PSTRIDE + idx),     c1 = *(const float4*)(P + PSTRIDE + idx + 4);
    float4 d0 = *(const float4*)(P + 2 * PSTRIDE + idx), d1 = *(const float4*)(P + 2 * PSTRIDE + idx + 4);
    float4 bb0 = *(const float4*)(b1 + col), bb1 = *(const float4*)(b1 + col + 4);
    float xs[8] = { a0.x + c0.x + d0.x + bb0.x, a0.y + c0.y + d0.y + bb0.y,
                    a0.z + c0.z + d0.z + bb0.z, a0.w + c0.w + d0.w + bb0.w,
                    a1.x + c1.x + d1.x + bb1.x, a1.y + c1.y + d1.y + bb1.y,
                    a1.z + c1.z + d1.z + bb1.z, a1.w + c1.w + d1.w + bb1.w };
    u16x8 v;
    #pragma unroll
    for (int p = 0; p < 8; ++p) {
        float x = xs[p];
        x = 0.5f * x * (1.0f + erff(x * 0.70710678118654752f));
        v[p] = f2bf(x);
    }
    *(u16x8*)(h + idx) = v;
}

// ---------------- finalize: out = base, blended on selected rows ----------------
__global__ __launch_bounds__(256) void finalize_kernel(
    const int* __restrict__ rmap,
    const float* __restrict__ gpart, const float* __restrict__ bg2,
    const float* __restrict__ base, const unsigned short* __restrict__ rl,
    float* __restrict__ out)
{
    const int lane = threadIdx.x & 63;
    const int row = blockIdx.x * 4 + (threadIdx.x >> 6);
    const int rm = rmap[row];

    const uint64_t bo = (uint64_t)row * D_;
    const float4* b4 = (const float4*)(base + bo);
    float4* o4 = (float4*)(out + bo);

    if (rm < 0) {
        #pragma unroll
        for (int i = 0; i < 3; ++i) o4[lane + 64 * i] = b4[lane + 64 * i];
        return;
    }
    const float4* gp = (const float4*)(gpart + (uint64_t)rm * 12);
    float4 g0 = gp[0], g1 = gp[1], g2 = gp[2];
    float sum = g0.x + g0.y + g0.z + g0.w + g1.x + g1.y + g1.z + g1.w
              + g2.x + g2.y + g2.z + g2.w + bg2[0];
    float gate = 1.0f / (1.0f + __expf(-sum));

    const u16x4* r4 = (const u16x4*)(rl + (uint64_t)rm * D_);
    #pragma unroll
    for (int i = 0; i < 3; ++i) {
        int idx = lane + 64 * i;
        float4 bb = b4[idx];
        u16x4 rr = r4[idx];
        float4 oo;
        oo.x = bb.x + gate * (bf2f(rr[0]) - bb.x);
        oo.y = bb.y + gate * (bf2f(rr[1]) - bb.y);
        oo.z = bb.z + gate * (bf2f(rr[2]) - bb.z);
        oo.w = bb.w + gate * (bf2f(rr[3]) - bb.w);
        o4[idx] = oo;
    }
}

extern "C" void kernel_launch(void* const* d_in, const int* in_sizes, int n_in,
                              void* d_out, int out_size, void* d_ws, size_t ws_size,
                              hipStream_t stream) {
    const float* base   = (const float*)d_in[0];
    const float* hires  = (const float*)d_in[1];
    const float* scores = (const float*)d_in[2];
    const float* W1  = (const float*)d_in[3];
    const float* b1  = (const float*)d_in[4];
    const float* W2  = (const float*)d_in[5];
    const float* b2  = (const float*)d_in[6];
    const float* Wg1 = (const float*)d_in[7];
    const float* bg1 = (const float*)d_in[8];
    const float* Wg2 = (const float*)d_in[9];
    const float* bg2 = (const float*)d_in[10];
    float* out = (float*)d_out;

    char* ws = (char*)d_ws;
    int*            sel   = (int*)(ws + OFF_SEL);
    int*            rmap  = (int*)(ws + OFF_RMAP);
    float*          gpart = (float*)(ws + OFF_GPART);
    unsigned short* W1t   = (unsigned short*)(ws + OFF_W1T);
    unsigned short* W2t   = (unsigned short*)(ws + OFF_W2T);
    unsigned short* Wg1t  = (unsigned short*)(ws + OFF_WG1T);
    unsigned short* Abase = (unsigned short*)(ws + OFF_ABASE);
    unsigned short* h     = (unsigned short*)(ws + OFF_H);
    unsigned short* rl    = (unsigned short*)(ws + OFF_RL);
    unsigned short* Aloc  = (unsigned short*)d_out;             // scratch until finalize
    float*          P0    = (float*)((char*)d_out + DOUT_P0);

    prep_kernel<<<dim3(NB + 126), dim3(1024), 0, stream>>>(scores, sel, rmap,
                                                           W1, W2, Wg1, W1t, W2t, Wg1t);
    gather_kernel<<<dim3(MSEL), dim3(256), 0, stream>>>(sel, hires, base, Aloc, Abase);
    gemm_mfma<0><<<dim3(8 * 10 * 3 * 3), dim3(256), 0, stream>>>(
        Aloc, nullptr, W1t, nullptr, nullptr, nullptr, nullptr, nullptr, nullptr, P0, nullptr);
    combine_kernel<<<dim3(924), dim3(256), 0, stream>>>(P0, b1, h);
    gemm_mfma<1><<<dim3(8 * 10 * 6), dim3(256), 0, stream>>>(
        h, nullptr, W2t, b2, nullptr, nullptr, nullptr, nullptr, rl, nullptr, nullptr);
    gemm_mfma<2><<<dim3(8 * 10 * 6), dim3(256), 0, stream>>>(
        Abase, rl, Wg1t, bg1, sel, scores, Wg1 + (uint64_t)1536 * HID, Wg2,
        nullptr, nullptr, gpart);
    finalize_kernel<<<dim3(NB * NTOK / 4), dim3(256), 0, stream>>>(rmap, gpart, bg2, base, rl, out);
}